// Round 4
// baseline (5174.657 us; speedup 1.0000x reference)
//
#include <hip/hip_runtime.h>
#include <math.h>

#define NB 128
#define NKK 64
#define ND 1536
#define NEM 512
#define NH 1024
#define NVOC 10000
#define NT 30

typedef __bf16 bf16x8 __attribute__((ext_vector_type(8)));
typedef __bf16 bf16x4 __attribute__((ext_vector_type(4)));
typedef float f32x4 __attribute__((ext_vector_type(4)));

__device__ __forceinline__ float sigf(float x) { return 1.0f / (1.0f + expf(-x)); }

#define GLOAD16(g, l)                                                     \
    __builtin_amdgcn_global_load_lds(                                     \
        (const __attribute__((address_space(1))) void*)(g),               \
        (__attribute__((address_space(3))) void*)(l), 16, 0, 0)

// ---------------- sort + target/lens + widx ----------------
__global__ void sort_kernel(const int* __restrict__ cap, const int* __restrict__ w,
                            float* __restrict__ out_target, float* __restrict__ out_lens,
                            int* __restrict__ order, int* __restrict__ lens_s,
                            int* __restrict__ widx) {
    __shared__ int lcap[NB];
    __shared__ int sord[NB];
    int b = threadIdx.x;
    lcap[b] = cap[b];
    __syncthreads();
    int lb = lcap[b];
    int pos = 0;
    for (int j = 0; j < NB; j++) {
        int lj = lcap[j];
        if (lj > lb || (lj == lb && j < b)) pos++;
    }
    sord[pos] = b;
    __syncthreads();
    int src = sord[b];
    order[b] = src;
    int ln = lcap[src] - 1;
    lens_s[b] = ln;
    out_lens[b] = (float)ln;
    for (int j = 0; j < NT; j++)
        out_target[b * NT + j] = (float)w[src * (NT + 1) + j + 1];
    for (int t = 0; t < NT; t++)
        widx[t * NB + b] = w[src * (NT + 1) + t];
}

// ---------------- init h_bf, c ----------------
__global__ void init_kernel(__bf16* __restrict__ h, float* __restrict__ c) {
    int tid = blockIdx.x * 256 + threadIdx.x;
    h[tid] = (__bf16)0.f;
    c[tid] = 0.f;
}

// ---------------- mean over K (sorted order), bf16 out ----------------
__global__ void meanim_kernel(const float* __restrict__ im, const int* __restrict__ order,
                              __bf16* __restrict__ meanb) {
    int b = blockIdx.x;
    int src = order[b];
    const float* base = im + (size_t)src * NKK * ND;
    for (int d = threadIdx.x; d < ND; d += 256) {
        float acc = 0.f;
        for (int k = 0; k < NKK; k++) acc += base[(size_t)k * ND + d];
        meanb[b * ND + d] = (__bf16)(acc * (1.0f / NKK));
    }
}

// ---------------- LDS-tiled transpose + f32->bf16 pack: dst[n][k] = src[k][n] ----------------
__global__ __launch_bounds__(256) void transpose_pack(
    const float* __restrict__ src, int ldn, int K, int N,
    __bf16* __restrict__ dst, int ldk) {
    __shared__ float tile[64][65];
    int k0 = blockIdx.y * 64, n0 = blockIdx.x * 64;
    int t = threadIdx.x;
    int kr = t >> 2, nc0 = (t & 3) * 16;
    int kk = k0 + kr;
#pragma unroll
    for (int j = 0; j < 16; j += 4) {
        int nn = n0 + nc0 + j;
        float4 v = make_float4(0.f, 0.f, 0.f, 0.f);
        if (kk < K && nn + 3 < N) v = *(const float4*)(src + (size_t)kk * ldn + nn);
        else if (kk < K) {
            float tmp[4] = {0.f, 0.f, 0.f, 0.f};
            for (int q = 0; q < 4; q++) if (nn + q < N) tmp[q] = src[(size_t)kk * ldn + nn + q];
            v = make_float4(tmp[0], tmp[1], tmp[2], tmp[3]);
        }
        tile[kr][nc0 + j + 0] = v.x; tile[kr][nc0 + j + 1] = v.y;
        tile[kr][nc0 + j + 2] = v.z; tile[kr][nc0 + j + 3] = v.w;
    }
    __syncthreads();
    int nr = t >> 2, kc0 = (t & 3) * 16;
    if (n0 + nr < N) {
        __bf16* drow = dst + (size_t)(n0 + nr) * ldk + k0 + kc0;
#pragma unroll
        for (int j = 0; j < 16; j++)
            if (k0 + kc0 + j < K) drow[j] = (__bf16)tile[kc0 + j][nr];
    }
}

// ---------------- f32 -> bf16 vector convert ----------------
__global__ void conv_bf16_vec(const float* __restrict__ src, __bf16* __restrict__ dst, int n4) {
    int id = blockIdx.x * 256 + threadIdx.x;
    if (id < n4) {
        float4 v = *(const float4*)(src + (size_t)id * 4);
        __bf16* d = dst + (size_t)id * 4;
        d[0] = (__bf16)v.x; d[1] = (__bf16)v.y; d[2] = (__bf16)v.z; d[3] = (__bf16)v.w;
    }
}

// ---------------- bias packs ----------------
__global__ void pack_biases(const float* __restrict__ b_ih, const float* __restrict__ b_hh,
                            const float* __restrict__ b_xg, const float* __restrict__ b_hg,
                            const float* __restrict__ bh, const float* __restrict__ bs,
                            float* __restrict__ bstep, float* __restrict__ b2) {
    int i = blockIdx.x * 256 + threadIdx.x;   // 0..5119
    if (i < 4096) bstep[i] = b_ih[i] + b_hh[i];
    else bstep[i] = b_xg[i - 4096] + b_hg[i - 4096];
    if (i < 1024) b2[i] = bh[i];
    else if (i < 2048) b2[i] = bs[i - 1024];
}

// =======================================================================
// gemm_ld: bf16-A MFMA GEMM with global_load_lds staging + counted vmcnt.
// LDS layout per buffer: As[kg][128][8], Bs[kg][64][8] (kg = k/8 within BK=64).
// AMODE 0: bf16 A [M][K] (M multiple of 128).
// AMODE 1: A rows = [emb(widx[b]) | g | h] concat, M=128, K=2048.
// =======================================================================
#define BM 128
#define BN 64
#define BK 64

template <int AMODE, bool RELU, bool OUTBF>
__global__ __launch_bounds__(256) void gemm_ld(
    const __bf16* __restrict__ Ab, int lda,
    const __bf16* __restrict__ Bt, int ldb,
    const float* __restrict__ bias,
    void* __restrict__ Cptr, int ldc,
    int M, int N, int K,
    size_t strideA, size_t strideB, size_t strideBias, size_t strideC,
    const __bf16* __restrict__ embb, const __bf16* __restrict__ gb,
    const __bf16* __restrict__ hb, const int* __restrict__ widx_t,
    int swz) {
    __shared__ __align__(16) __bf16 As[2 * 8 * BM * 8];   // 32 KB
    __shared__ __align__(16) __bf16 Bs[2 * 8 * BN * 8];   // 16 KB

    const int t = threadIdx.x;
    const int lane = t & 63;
    const int wid = t >> 6;
    const int wr = wid >> 1, wc = wid & 1;
    const int lr = lane & 15, lg = lane >> 4;

    int bx = blockIdx.x, by = blockIdx.y;
    if (swz) {  // XCD-aware: all n-blocks of an m-panel on one XCD (gridDim.y % 8 == 0)
        int L = by * gridDim.x + bx;
        int xcd = L & 7, q = L >> 3;
        by = xcd * (gridDim.y >> 3) + q / gridDim.x;
        bx = q % gridDim.x;
    }
    const int m0 = by * BM;
    const int n0 = bx * BN;
    const int z = blockIdx.z;

    f32x4 acc[4][2];
#pragma unroll
    for (int i = 0; i < 4; i++)
#pragma unroll
        for (int j = 0; j < 2; j++) acc[i][j] = (f32x4){0.f, 0.f, 0.f, 0.f};

    const __bf16* Az = (AMODE == 0) ? Ab + z * strideA : nullptr;
    const __bf16* Bz = Bt + z * strideB;
    const int bcol = (n0 + lane < N) ? (n0 + lane) : (N - 1);
    const __bf16* b_base = Bz + (size_t)bcol * ldb;

    int w_lo = 0, w_hi = 0;
    if (AMODE == 1) { w_lo = widx_t[lane]; w_hi = widx_t[64 + lane]; }

    auto issueStage = [&](int s, int buf) {
        const int k0 = s * BK;
        __bf16* Ad = &As[buf * 8192];
        __bf16* Bd = &Bs[buf * 4096];
#pragma unroll
        for (int i = 0; i < 4; i++) {
            const int idx = wid * 4 + i;          // 0..15
            const int kg = idx >> 1;              // 0..7
            const int row = ((idx & 1) << 6) + lane;
            const __bf16* src;
            if (AMODE == 0) {
                src = Az + (size_t)(m0 + row) * lda + k0 + kg * 8;
            } else {
                if (k0 < NEM)
                    src = embb + (size_t)((idx & 1) ? w_hi : w_lo) * NEM + k0 + kg * 8;
                else if (k0 < 2 * NEM)
                    src = gb + (size_t)row * NEM + (k0 - NEM) + kg * 8;
                else
                    src = hb + (size_t)row * NH + (k0 - 2 * NEM) + kg * 8;
            }
            GLOAD16(src, Ad + idx * 512);
        }
#pragma unroll
        for (int i = 0; i < 2; i++) {
            const int idx = wid * 2 + i;          // 0..7 = kg
            const __bf16* src = b_base + k0 + idx * 8;
            GLOAD16(src, Bd + idx * 512);
        }
    };

    const int S = K / BK;
    issueStage(0, 0);
    for (int s = 0; s < S; ++s) {
        if (s + 1 < S) {
            issueStage(s + 1, (s + 1) & 1);
            asm volatile("s_waitcnt vmcnt(6)" ::: "memory");
        } else {
            asm volatile("s_waitcnt vmcnt(0)" ::: "memory");
        }
        __builtin_amdgcn_s_barrier();
        asm volatile("" ::: "memory");
        const int bA = (s & 1) * 8192, bB = (s & 1) * 4096;
#pragma unroll
        for (int ks = 0; ks < 2; ++ks) {
            const int kg = ks * 4 + lg;
            const int arow = wr * 64 + lr;
            const int bcol2 = wc * 32 + lr;
            bf16x8 af0 = *(const bf16x8*)&As[bA + (kg * 128 + arow + 0) * 8];
            bf16x8 af1 = *(const bf16x8*)&As[bA + (kg * 128 + arow + 16) * 8];
            bf16x8 af2 = *(const bf16x8*)&As[bA + (kg * 128 + arow + 32) * 8];
            bf16x8 af3 = *(const bf16x8*)&As[bA + (kg * 128 + arow + 48) * 8];
            bf16x8 bv0 = *(const bf16x8*)&Bs[bB + (kg * 64 + bcol2 + 0) * 8];
            bf16x8 bv1 = *(const bf16x8*)&Bs[bB + (kg * 64 + bcol2 + 16) * 8];
            acc[0][0] = __builtin_amdgcn_mfma_f32_16x16x32_bf16(af0, bv0, acc[0][0], 0, 0, 0);
            acc[0][1] = __builtin_amdgcn_mfma_f32_16x16x32_bf16(af0, bv1, acc[0][1], 0, 0, 0);
            acc[1][0] = __builtin_amdgcn_mfma_f32_16x16x32_bf16(af1, bv0, acc[1][0], 0, 0, 0);
            acc[1][1] = __builtin_amdgcn_mfma_f32_16x16x32_bf16(af1, bv1, acc[1][1], 0, 0, 0);
            acc[2][0] = __builtin_amdgcn_mfma_f32_16x16x32_bf16(af2, bv0, acc[2][0], 0, 0, 0);
            acc[2][1] = __builtin_amdgcn_mfma_f32_16x16x32_bf16(af2, bv1, acc[2][1], 0, 0, 0);
            acc[3][0] = __builtin_amdgcn_mfma_f32_16x16x32_bf16(af3, bv0, acc[3][0], 0, 0, 0);
            acc[3][1] = __builtin_amdgcn_mfma_f32_16x16x32_bf16(af3, bv1, acc[3][1], 0, 0, 0);
        }
        asm volatile("" ::: "memory");
        __builtin_amdgcn_s_barrier();
    }

    // ---- epilogue ----
    const float* bias_z = bias + z * strideBias;
    float* Cf = (float*)Cptr + z * strideC;
    __bf16* Cb = (__bf16*)Cptr + z * strideC;
#pragma unroll
    for (int mi = 0; mi < 4; mi++) {
#pragma unroll
        for (int ni = 0; ni < 2; ni++) {
            int col = n0 + wc * 32 + ni * 16 + lr;
            if (col < N) {
                float bb = bias_z[col];
#pragma unroll
                for (int rr = 0; rr < 4; rr++) {
                    int row = m0 + wr * 64 + mi * 16 + lg * 4 + rr;
                    float v = acc[mi][ni][rr] + bb;
                    if (RELU) v = fmaxf(v, 0.f);
                    if (OUTBF) Cb[(size_t)row * ldc + col] = (__bf16)v;
                    else Cf[(size_t)row * ldc + col] = v;
                }
            }
        }
    }
}

// ---------------- old register-staged GEMM (f32-A path, used for V only) ----------------
template <bool RELU, bool OUTBF>
__global__ __launch_bounds__(256) void gemm_bt(
    const float* __restrict__ Aptr, int lda,
    const __bf16* __restrict__ Bt, int ldb,
    const float* __restrict__ bias,
    void* __restrict__ Cptr, int ldc,
    int M, int N, int K,
    const int* __restrict__ order, int swz) {
    const int t = threadIdx.x;
    const int lane = t & 63;
    const int wid = t >> 6;
    const int wr = wid >> 1, wc = wid & 1;
    int bx = blockIdx.x, by = blockIdx.y;
    if (swz) {
        int L = by * gridDim.x + bx;
        int xcd = L & 7, q = L >> 3;
        by = xcd * (gridDim.y >> 3) + q / gridDim.x;
        bx = q % gridDim.x;
    }
    const int m0 = by * BM;
    const int n0 = bx * BN;
    const int lr = lane & 15, lg = lane >> 4, lr8 = lr & 7;

    __shared__ __bf16 As[BM * BK];
    __shared__ __bf16 Bs[BN * BK];

    f32x4 acc[4][2];
#pragma unroll
    for (int i = 0; i < 4; i++)
#pragma unroll
        for (int j = 0; j < 2; j++) acc[i][j] = (f32x4){0.f, 0.f, 0.f, 0.f};

    const int s_row = t >> 1;
    const int s_g0 = (t & 1) * 4;
    const int s_col = t >> 2;
    const int s_bg0 = (t & 3) * 2;
    const int r8 = s_row & 7, c8 = s_col & 7;
    const int aw0 = (s_row << 6) + (((s_g0 + 0) ^ r8) << 3);
    const int aw1 = (s_row << 6) + (((s_g0 + 1) ^ r8) << 3);
    const int aw2 = (s_row << 6) + (((s_g0 + 2) ^ r8) << 3);
    const int aw3 = (s_row << 6) + (((s_g0 + 3) ^ r8) << 3);
    const int bw0 = (s_col << 6) + (((s_bg0 + 0) ^ c8) << 3);
    const int bw1 = (s_col << 6) + (((s_bg0 + 1) ^ c8) << 3);
    const int rA0 = (wr * 64 + 0 * 16 + lr) << 6;
    const int rA1 = (wr * 64 + 1 * 16 + lr) << 6;
    const int rA2 = (wr * 64 + 2 * 16 + lr) << 6;
    const int rA3 = (wr * 64 + 3 * 16 + lr) << 6;
    const int cB0 = (wc * 32 + 0 * 16 + lr) << 6;
    const int cB1 = (wc * 32 + 1 * 16 + lr) << 6;

    int gr = m0 + s_row;
    int srow = order[gr >> 6] * 64 + (gr & 63);
    const float* a_srcf = Aptr + (size_t)srow * lda + s_g0 * 8;
    const __bf16* b_src = Bt + (size_t)(n0 + s_col) * ldb + s_bg0 * 8;
    const bool b_ok = (n0 + s_col) < N;

    auto loadA = [&](int k0, bf16x8& a0, bf16x8& a1, bf16x8& a2, bf16x8& a3) {
        const float4* p = (const float4*)(a_srcf + k0);
        float4 f0 = p[0], f1 = p[1], f2 = p[2], f3 = p[3];
        float4 f4 = p[4], f5 = p[5], f6 = p[6], f7 = p[7];
        a0 = (bf16x8){(__bf16)f0.x, (__bf16)f0.y, (__bf16)f0.z, (__bf16)f0.w,
                      (__bf16)f1.x, (__bf16)f1.y, (__bf16)f1.z, (__bf16)f1.w};
        a1 = (bf16x8){(__bf16)f2.x, (__bf16)f2.y, (__bf16)f2.z, (__bf16)f2.w,
                      (__bf16)f3.x, (__bf16)f3.y, (__bf16)f3.z, (__bf16)f3.w};
        a2 = (bf16x8){(__bf16)f4.x, (__bf16)f4.y, (__bf16)f4.z, (__bf16)f4.w,
                      (__bf16)f5.x, (__bf16)f5.y, (__bf16)f5.z, (__bf16)f5.w};
        a3 = (bf16x8){(__bf16)f6.x, (__bf16)f6.y, (__bf16)f6.z, (__bf16)f6.w,
                      (__bf16)f7.x, (__bf16)f7.y, (__bf16)f7.z, (__bf16)f7.w};
    };
    auto loadB = [&](int k0, bf16x8& b0, bf16x8& b1) {
        if (b_ok) {
            const bf16x8* p = (const bf16x8*)(b_src + k0);
            b0 = p[0]; b1 = p[1];
        } else {
            bf16x8 zv = {};
            b0 = zv; b1 = zv;
        }
    };
    auto writeS = [&](bf16x8 a0, bf16x8 a1, bf16x8 a2, bf16x8 a3, bf16x8 b0, bf16x8 b1) {
        *(bf16x8*)&As[aw0] = a0; *(bf16x8*)&As[aw1] = a1;
        *(bf16x8*)&As[aw2] = a2; *(bf16x8*)&As[aw3] = a3;
        *(bf16x8*)&Bs[bw0] = b0; *(bf16x8*)&Bs[bw1] = b1;
    };
    auto compute = [&]() {
#pragma unroll
        for (int ks = 0; ks < 2; ks++) {
            const int gsw = ((ks * 4 + lg) ^ lr8) << 3;
            bf16x8 af0 = *(const bf16x8*)&As[rA0 + gsw];
            bf16x8 af1 = *(const bf16x8*)&As[rA1 + gsw];
            bf16x8 af2 = *(const bf16x8*)&As[rA2 + gsw];
            bf16x8 af3 = *(const bf16x8*)&As[rA3 + gsw];
            bf16x8 bv0 = *(const bf16x8*)&Bs[cB0 + gsw];
            bf16x8 bv1 = *(const bf16x8*)&Bs[cB1 + gsw];
            acc[0][0] = __builtin_amdgcn_mfma_f32_16x16x32_bf16(af0, bv0, acc[0][0], 0, 0, 0);
            acc[0][1] = __builtin_amdgcn_mfma_f32_16x16x32_bf16(af0, bv1, acc[0][1], 0, 0, 0);
            acc[1][0] = __builtin_amdgcn_mfma_f32_16x16x32_bf16(af1, bv0, acc[1][0], 0, 0, 0);
            acc[1][1] = __builtin_amdgcn_mfma_f32_16x16x32_bf16(af1, bv1, acc[1][1], 0, 0, 0);
            acc[2][0] = __builtin_amdgcn_mfma_f32_16x16x32_bf16(af2, bv0, acc[2][0], 0, 0, 0);
            acc[2][1] = __builtin_amdgcn_mfma_f32_16x16x32_bf16(af2, bv1, acc[2][1], 0, 0, 0);
            acc[3][0] = __builtin_amdgcn_mfma_f32_16x16x32_bf16(af3, bv0, acc[3][0], 0, 0, 0);
            acc[3][1] = __builtin_amdgcn_mfma_f32_16x16x32_bf16(af3, bv1, acc[3][1], 0, 0, 0);
        }
    };

    bf16x8 a0, a1, a2, a3, b0, b1;
    bf16x8 c0, c1, c2, c3, d0, d1;
    loadA(0, a0, a1, a2, a3);
    loadB(0, b0, b1);
    for (int k0 = 0; k0 < K; k0 += 2 * BK) {
        writeS(a0, a1, a2, a3, b0, b1);
        __syncthreads();
        loadA(k0 + BK, c0, c1, c2, c3);
        loadB(k0 + BK, d0, d1);
        compute();
        __syncthreads();
        writeS(c0, c1, c2, c3, d0, d1);
        __syncthreads();
        if (k0 + 2 * BK < K) {
            loadA(k0 + 2 * BK, a0, a1, a2, a3);
            loadB(k0 + 2 * BK, b0, b1);
        }
        compute();
        __syncthreads();
    }

    float* Cf = (float*)Cptr;
    __bf16* Cb = (__bf16*)Cptr;
#pragma unroll
    for (int mi = 0; mi < 4; mi++) {
#pragma unroll
        for (int ni = 0; ni < 2; ni++) {
            int col = n0 + wc * 32 + ni * 16 + lr;
            if (col < N) {
                float bb = bias[col];
#pragma unroll
                for (int rr = 0; rr < 4; rr++) {
                    int row = m0 + wr * 64 + mi * 16 + lg * 4 + rr;
                    float v = acc[mi][ni][rr] + bb;
                    if (RELU) v = fmaxf(v, 0.f);
                    if (OUTBF) Cb[(size_t)row * ldc + col] = (__bf16)v;
                    else Cf[(size_t)row * ldc + col] = v;
                }
            }
        }
    }
}

// ---------------- LSTM pointwise ----------------
__global__ void lstm_pointwise(const float* __restrict__ gates, float* __restrict__ c,
                               __bf16* __restrict__ h, __bf16* __restrict__ s) {
    int tid = blockIdx.x * 256 + threadIdx.x;   // b*NH + j
    int b = tid >> 10, j = tid & 1023;
    const float* gr = gates + (size_t)b * 5120;
    float ig = sigf(gr[j]);
    float fg = sigf(gr[1024 + j]);
    float gg = tanhf(gr[2048 + j]);
    float og = sigf(gr[3072 + j]);
    float sgg = sigf(gr[4096 + j]);
    float cn = fg * c[tid] + ig * gg;
    float tc = tanhf(cn);
    c[tid] = cn;
    h[tid] = (__bf16)(og * tc);
    s[tid] = (__bf16)(sgg * tc);
}

// ---------------- attention ----------------
__global__ __launch_bounds__(256) void attn_kernel(
    const __bf16* __restrict__ VA, const __bf16* __restrict__ V,
    const float* __restrict__ hp, const float* __restrict__ sws,
    const float* __restrict__ wa, const __bf16* __restrict__ s,
    const __bf16* __restrict__ h, __bf16* __restrict__ z) {
    __shared__ float zscore[NKK + 1];
    __shared__ float alpha_s[NKK + 1];
    int b = blockIdx.x;
    int wave = threadIdx.x >> 6, lane = threadIdx.x & 63;

    float hp_reg[16], wa_reg[16];
    {
        const float* hb2 = hp + (size_t)b * NH + lane * 16;
        const float* wb = wa + lane * 16;
#pragma unroll
        for (int q = 0; q < 4; q++) {
            float4 hv = *(const float4*)(hb2 + q * 4);
            float4 wv = *(const float4*)(wb + q * 4);
            hp_reg[q * 4 + 0] = hv.x; hp_reg[q * 4 + 1] = hv.y;
            hp_reg[q * 4 + 2] = hv.z; hp_reg[q * 4 + 3] = hv.w;
            wa_reg[q * 4 + 0] = wv.x; wa_reg[q * 4 + 1] = wv.y;
            wa_reg[q * 4 + 2] = wv.z; wa_reg[q * 4 + 3] = wv.w;
        }
    }
    for (int k = wave; k <= NKK; k += 4) {
        float p = 0.f;
        if (k < NKK) {
            const bf16x8* row = (const bf16x8*)(VA + ((size_t)(b * NKK + k)) * NH + lane * 16);
            bf16x8 v0 = row[0], v1 = row[1];
#pragma unroll
            for (int j = 0; j < 8; j++) {
                p += tanhf((float)v0[j] + hp_reg[j]) * wa_reg[j];
                p += tanhf((float)v1[j] + hp_reg[8 + j]) * wa_reg[8 + j];
            }
        } else {
            const float* sp = sws + (size_t)b * NH + lane * 16;
#pragma unroll
            for (int j = 0; j < 16; j++) p += tanhf(sp[j] + hp_reg[j]) * wa_reg[j];
        }
        for (int off = 32; off; off >>= 1) p += __shfl_down(p, off);
        if (lane == 0) zscore[k] = p;
    }
    __syncthreads();
    if (threadIdx.x == 0) {
        float mx = zscore[0];
        for (int i = 1; i <= NKK; i++) mx = fmaxf(mx, zscore[i]);
        float ssum = 0.f;
        for (int i = 0; i <= NKK; i++) { float e = expf(zscore[i] - mx); alpha_s[i] = e; ssum += e; }
        float inv = 1.f / ssum;
        for (int i = 0; i <= NKK; i++) alpha_s[i] *= inv;
    }
    __syncthreads();
    float beta = alpha_s[NKK];
    for (int jj = threadIdx.x; jj < NH; jj += 256) {
        float ctx = 0.f;
        const __bf16* vp = V + ((size_t)b * NKK) * NH + jj;
#pragma unroll 8
        for (int k = 0; k < NKK; k++) ctx += alpha_s[k] * (float)vp[(size_t)k * NH];
        float zv = beta * (float)s[b * NH + jj] + (1.f - beta) * ctx + (float)h[b * NH + jj];
        z[b * NH + jj] = (__bf16)zv;
    }
}

// ---------------- vocab softmax + mask (2-pass, LDS exp cache) ----------------
__global__ __launch_bounds__(256) void vocab_softmax(const float* __restrict__ logits,
                                                     const int* __restrict__ lens_s, int t,
                                                     float* __restrict__ pred) {
    __shared__ float se[NVOC];
    int b = blockIdx.x;
    float* out = pred + (size_t)b * NT * NVOC + (size_t)t * NVOC;
    if (t >= lens_s[b]) {
        for (int v = threadIdx.x; v < NVOC; v += 256) out[v] = 0.f;
        return;
    }
    const float* lg = logits + (size_t)b * NVOC;
    float mx = -1e30f;
    for (int v = threadIdx.x; v < NVOC; v += 256) {
        float x = lg[v];
        se[v] = x;
        mx = fmaxf(mx, x);
    }
    __shared__ float sred[4];
    for (int off = 32; off; off >>= 1) mx = fmaxf(mx, __shfl_down(mx, off));
    if ((threadIdx.x & 63) == 0) sred[threadIdx.x >> 6] = mx;
    __syncthreads();
    mx = fmaxf(fmaxf(sred[0], sred[1]), fmaxf(sred[2], sred[3]));
    float ssum = 0.f;
    for (int v = threadIdx.x; v < NVOC; v += 256) {
        float e = expf(se[v] - mx);
        se[v] = e;
        ssum += e;
    }
    for (int off = 32; off; off >>= 1) ssum += __shfl_down(ssum, off);
    __shared__ float sred2[4];
    if ((threadIdx.x & 63) == 0) sred2[threadIdx.x >> 6] = ssum;
    __syncthreads();
    ssum = sred2[0] + sred2[1] + sred2[2] + sred2[3];
    float inv = 1.f / ssum;
    for (int v = threadIdx.x; v < NVOC; v += 256) out[v] = se[v] * inv;
}

extern "C" void kernel_launch(void* const* d_in, const int* in_sizes, int n_in,
                              void* d_out, int out_size, void* d_ws, size_t ws_size,
                              hipStream_t stream) {
    const float* im = (const float*)d_in[0];
    const int* w_in = (const int*)d_in[1];
    const int* cap = (const int*)d_in[2];
    const float* emb = (const float*)d_in[3];
    const float* W_enc = (const float*)d_in[4];
    const float* b_enc = (const float*)d_in[5];
    const float* W_glob = (const float*)d_in[6];
    const float* b_glob = (const float*)d_in[7];
    const float* W_ih = (const float*)d_in[8];
    const float* b_ih = (const float*)d_in[9];
    const float* W_hh = (const float*)d_in[10];
    const float* b_hh = (const float*)d_in[11];
    const float* W_xg = (const float*)d_in[12];
    const float* b_xg = (const float*)d_in[13];
    const float* W_hg = (const float*)d_in[14];
    const float* b_hg = (const float*)d_in[15];
    const float* Wv = (const float*)d_in[16];
    const float* bv = (const float*)d_in[17];
    const float* Ws = (const float*)d_in[18];
    const float* bs = (const float*)d_in[19];
    const float* Wh = (const float*)d_in[20];
    const float* bh = (const float*)d_in[21];
    const float* wa = (const float*)d_in[22];
    // ba cancels in softmax(65)
    const float* W_out = (const float*)d_in[24];
    const float* b_out = (const float*)d_in[25];

    float* out = (float*)d_out;
    float* pred = out;
    float* out_target = out + (size_t)NB * NT * NVOC;
    float* out_lens = out_target + NB * NT;

    char* p = (char*)d_ws;
    size_t off = 0;
    auto carve = [&](size_t bytes) {
        void* r = p + off;
        off += (bytes + 255) & ~(size_t)255;
        return r;
    };
    int* order = (int*)carve(NB * 4);
    int* lens_s = (int*)carve(NB * 4);
    int* widx = (int*)carve(NT * NB * 4);
    __bf16* embb = (__bf16*)carve((size_t)NVOC * NEM * 2);
    __bf16* Wstep_t = (__bf16*)carve((size_t)5120 * 2048 * 2);
    __bf16* W2t = (__bf16*)carve((size_t)2 * 1024 * 1024 * 2);
    __bf16* Wout_t = (__bf16*)carve((size_t)NVOC * 1024 * 2);
    __bf16* Wglob_t = (__bf16*)carve((size_t)512 * 1536 * 2);
    __bf16* Wenc_t = (__bf16*)carve((size_t)1024 * 1536 * 2);
    __bf16* Wv_t = (__bf16*)carve((size_t)1024 * 1024 * 2);
    float* bstep = (float*)carve(5120 * 4);
    float* b2 = (float*)carve(2048 * 4);
    __bf16* meanb = (__bf16*)carve((size_t)NB * ND * 2);
    __bf16* g_bf = (__bf16*)carve((size_t)NB * NEM * 2);
    __bf16* V_bf = (__bf16*)carve((size_t)NB * NKK * NH * 2);
    __bf16* VA_bf = (__bf16*)carve((size_t)NB * NKK * NH * 2);
    float* gates = (float*)carve((size_t)NB * 5120 * 4);
    __bf16* hs_bf = (__bf16*)carve((size_t)2 * NB * NH * 2);   // [h ; s]
    float* c = (float*)carve((size_t)NB * NH * 4);
    float* hpsws = (float*)carve((size_t)2 * NB * NH * 4);     // [hp ; sws]
    __bf16* z_bf = (__bf16*)carve((size_t)NB * NH * 2);
    float* logits = (float*)carve((size_t)NB * NVOC * 4);
    if (off > ws_size) return;  // fail loudly via absmax if ws too small

    __bf16* h_bf = hs_bf;
    __bf16* s_bf = hs_bf + (size_t)NB * NH;
    float* hp = hpsws;
    float* sws = hpsws + (size_t)NB * NH;

    // ---- one-time setup ----
    sort_kernel<<<1, NB, 0, stream>>>(cap, w_in, out_target, out_lens, order, lens_s, widx);
    init_kernel<<<(NB * NH) / 256, 256, 0, stream>>>(h_bf, c);
    pack_biases<<<20, 256, 0, stream>>>(b_ih, b_hh, b_xg, b_hg, bh, bs, bstep, b2);
    conv_bf16_vec<<<(NVOC * NEM / 4 + 255) / 256, 256, 0, stream>>>(emb, embb, NVOC * NEM / 4);
    transpose_pack<<<dim3(8, 24), 256, 0, stream>>>(W_glob, 512, 1536, 512, Wglob_t, 1536);
    transpose_pack<<<dim3(16, 24), 256, 0, stream>>>(W_enc, 1024, 1536, 1024, Wenc_t, 1536);
    transpose_pack<<<dim3(16, 16), 256, 0, stream>>>(Wv, 1024, 1024, 1024, Wv_t, 1024);
    transpose_pack<<<dim3(64, 16), 256, 0, stream>>>(W_ih, 4096, 1024, 4096, Wstep_t, 2048);
    transpose_pack<<<dim3(64, 16), 256, 0, stream>>>(W_hh, 4096, 1024, 4096, Wstep_t + 1024, 2048);
    transpose_pack<<<dim3(16, 16), 256, 0, stream>>>(W_xg, 1024, 1024, 1024,
                                                     Wstep_t + (size_t)4096 * 2048, 2048);
    transpose_pack<<<dim3(16, 16), 256, 0, stream>>>(W_hg, 1024, 1024, 1024,
                                                     Wstep_t + (size_t)4096 * 2048 + 1024, 2048);
    transpose_pack<<<dim3(16, 16), 256, 0, stream>>>(Wh, 1024, 1024, 1024, W2t, 1024);
    transpose_pack<<<dim3(16, 16), 256, 0, stream>>>(Ws, 1024, 1024, 1024, W2t + (size_t)1024 * 1024, 1024);
    transpose_pack<<<dim3(157, 16), 256, 0, stream>>>(W_out, NVOC, 1024, NVOC, Wout_t, 1024);
    meanim_kernel<<<NB, 256, 0, stream>>>(im, order, meanb);

    // g = relu(meanim @ W_glob + b_glob)   (128 x 512, K=1536), bf16 out
    gemm_ld<0, true, true><<<dim3(NEM / BN, 1), 256, 0, stream>>>(
        meanb, ND, Wglob_t, ND, b_glob, g_bf, NEM, NB, NEM, ND, 0, 0, 0, 0,
        nullptr, nullptr, nullptr, nullptr, 0);
    // V = relu(im[order] @ W_enc + b_enc)  (8192 x 1024, K=1536), bf16 out (f32 A, old path + swizzle)
    gemm_bt<true, true><<<dim3(NH / BN, (NB * NKK) / BM), 256, 0, stream>>>(
        im, ND, Wenc_t, ND, b_enc, V_bf, NH, NB * NKK, NH, ND, order, 1);
    // VA = V @ Wv + bv                     (8192 x 1024, K=1024), bf16 out
    gemm_ld<0, false, true><<<dim3(NH / BN, (NB * NKK) / BM), 256, 0, stream>>>(
        V_bf, NH, Wv_t, NH, bv, VA_bf, NH, NB * NKK, NH, NH, 0, 0, 0, 0,
        nullptr, nullptr, nullptr, nullptr, 1);

    // ---- 30 timesteps ----
    for (int t = 0; t < NT; t++) {
        // gates|sg = [emb|g|h] @ Wstep + bstep   (128 x 5120, K=2048), f32 out
        gemm_ld<1, false, false><<<dim3(5120 / BN, 1), 256, 0, stream>>>(
            nullptr, 0, Wstep_t, 2048, bstep, gates, 5120, NB, 5120, 2048, 0, 0, 0, 0,
            embb, g_bf, h_bf, widx + t * NB, 0);
        lstm_pointwise<<<(NB * NH) / 256, 256, 0, stream>>>(gates, c, h_bf, s_bf);
        // [hp ; sws] = [h ; s] @ [Wh ; Ws] + [bh ; bs]   (z-batched, f32 out)
        gemm_ld<0, false, false><<<dim3(NH / BN, 1, 2), 256, 0, stream>>>(
            hs_bf, NH, W2t, NH, b2, hpsws, NH, NB, NH, NH,
            (size_t)NB * NH, (size_t)NH * NH, (size_t)NH, (size_t)NB * NH,
            nullptr, nullptr, nullptr, nullptr, 0);
        attn_kernel<<<NB, 256, 0, stream>>>(VA_bf, V_bf, hp, sws, wa, s_bf, h_bf, z_bf);
        // logits = z @ W_out + b_out        (128 x 10000, K=1024), f32 out
        gemm_ld<0, false, false><<<dim3((NVOC + BN - 1) / BN, 1), 256, 0, stream>>>(
            z_bf, NH, Wout_t, NH, b_out, logits, NVOC, NB, NVOC, NH, 0, 0, 0, 0,
            nullptr, nullptr, nullptr, nullptr, 0);
        vocab_softmax<<<NB, 256, 0, stream>>>(logits, lens_s, t, pred);
    }
}